// Round 6
// baseline (122.093 us; speedup 1.0000x reference)
//
#include <hip/hip_runtime.h>
#include <hip/hip_bf16.h>

// Conv2dKan via implicit-GEMM MFMA (32x32x16 bf16). b=16, cin=cout=64, H=W=32, K=3, PAD=1, BASIS=8.
// out[b,o,pix] = bias[o] + sum_{i,k,s8} Wt[i,k,o,s]*Ah[b,i,pix+off(k),s]
//   Wt[...,0]=w, Wt[...,s]=w*c[s] (s=1..7), bf16   layout [i][kpos][o][s]
//   Ah = [silu(x), T1..T7(tanh x)] on 34x34 halo grid; border = act(0) = [0,0,-1,0,1,0,-1,0]
//   bias[o] = sum_{i,k} w*c[...,0]  (T0==1)
// MFMA 32x32x16: A=weights (M=32 o), B=activations (N=32 pix), K=16 = chpair x 8 s.
//   A/B frag: elem j, k=(lane>>5)*8+j, m/n=lane&31   [verified by R5 pass]
//   C/D: col(pix)=lane&31, row(o)=(r&3)+8*(r>>2)+4*(lane>>5)
// R6: TLP fix. Wave = 64o x 32pix (each af feeds 2 MFMAs); split-K=4 over grid.z
//     (16ch each) -> 2048 waves = 2/SIMD, 2 blocks/CU. fp32 atomicAdd epilogue;
//     kq==0 adds bias; d_out zeroed in fused prep/act launch. 4 acc chains.

#define CIN   64
#define COUT  64
#define HW    32
#define LL    1024
#define NS    8
#define AH    34
#define AHC   1156

typedef __attribute__((ext_vector_type(8))) short short8;
typedef __attribute__((ext_vector_type(16))) float f32x16;

// ws layout (bytes):
//   [0)       Wt   : 64*9*64*8 bf16 = 589824 B   ([i][kpos][o][s])
//   [589824)  bias : 64 f32         = 256 B
//   [590080)  Ah   : 16*64*1156*8 bf16 = 18939904 B

__global__ void prep_act_kernel(const float* __restrict__ x,
                                const float* __restrict__ w,
                                const float* __restrict__ c,
                                __hip_bfloat16* __restrict__ Wt,
                                float* __restrict__ bias,
                                __hip_bfloat16* __restrict__ Ah,
                                float* __restrict__ out) {
    int bx = blockIdx.x;
    if (bx >= 4624) {
        bx -= 4624;
        if (bx < 4096) {                 // init part: zero d_out (atomic target)
            out[bx * 256 + threadIdx.x] = 0.f;
            return;
        }
        bx -= 4096;                      // prep part: 145 blocks
        if (bx == 144) {
            // bias[o] = sum_{i,k} w[i,o,k]*c[i,o,k,0]
            __shared__ float red[256];
            const int o = threadIdx.x & 63;
            const int part = threadIdx.x >> 6;
            float v = 0.f;
            for (int ii = 0; ii < 16; ++ii) {
                const int i = part * 16 + ii;
#pragma unroll
                for (int k = 0; k < 9; ++k) {
                    const int idx = (i * COUT + o) * 9 + k;
                    v += w[idx] * c[idx * 8];
                }
            }
            red[threadIdx.x] = v;
            __syncthreads();
            if (part == 0) bias[o] = red[o] + red[64 + o] + red[128 + o] + red[192 + o];
            return;
        }
        const int tid = bx * 256 + threadIdx.x;   // < 36864 = 64i*9k*64o
        const int i = tid / (9 * COUT);
        const int r = tid - i * 9 * COUT;
        const int k = r / COUT;
        const int o = r - k * COUT;
        const int widx = (i * COUT + o) * 9 + k;
        const float wv = w[widx];
        __hip_bfloat16* dst = Wt + (size_t)tid * NS;   // tid == (i*9+k)*64+o
        dst[0] = __float2bfloat16(wv);
#pragma unroll
        for (int s = 1; s < 8; ++s) dst[s] = __float2bfloat16(wv * c[widx * 8 + s]);
        return;
    }

    // act part: 4624 blocks, 1,183,744 threads = 16*64*1156 halo cells
    const int idx = bx * 256 + threadIdx.x;
    const int bi = idx / AHC;
    const int r  = idx - bi * AHC;
    const int yy = r / AH;
    const int xx = r - yy * AH;
    __align__(16) __hip_bfloat16 hv[8];
    if (yy >= 1 && yy <= 32 && xx >= 1 && xx <= 32) {
        float xv = x[bi * LL + (yy - 1) * HW + (xx - 1)];
        float e  = __expf(-xv);
        float res = xv / (1.f + e);              // silu
        float e2 = __expf(2.f * xv);
        float t  = 1.f - 2.f / (e2 + 1.f);       // tanh
        float T2 = 2.f * t * t  - 1.f;
        float T3 = 2.f * t * T2 - t;
        float T4 = 2.f * t * T3 - T2;
        float T5 = 2.f * t * T4 - T3;
        float T6 = 2.f * t * T5 - T4;
        float T7 = 2.f * t * T6 - T5;
        hv[0] = __float2bfloat16(res); hv[1] = __float2bfloat16(t);
        hv[2] = __float2bfloat16(T2);  hv[3] = __float2bfloat16(T3);
        hv[4] = __float2bfloat16(T4);  hv[5] = __float2bfloat16(T5);
        hv[6] = __float2bfloat16(T6);  hv[7] = __float2bfloat16(T7);
    } else {
        // activation of x=0: [0, 0, -1, 0, 1, 0, -1, 0]
        ((unsigned int*)hv)[0] = 0x00000000u;
        ((unsigned int*)hv)[1] = 0x0000BF80u;
        ((unsigned int*)hv)[2] = 0x00003F80u;
        ((unsigned int*)hv)[3] = 0x0000BF80u;
    }
    *(float4*)(Ah + (size_t)idx * NS) = *(const float4*)hv;
}

// grid (8 row-quads, 16 batches, 4 K-quarters), block 256 = 4 waves (one row each).
// Wave tile: 64 o x 32 pix (one image row), K-quarter = 16 ch = 2 ig of 8 ch.
__global__ __launch_bounds__(256) void kan_mfma_kernel(
        const __hip_bfloat16* __restrict__ Wt,
        const float* __restrict__ bias,
        const __hip_bfloat16* __restrict__ Ah,
        float* __restrict__ out) {
    __shared__ __align__(16) unsigned short Wlds[36864];   // 8ch x 9k x 64o x 8s = 73728 B

    const int tid  = threadIdx.x;
    const int wv   = tid >> 6;
    const int lane = tid & 63;
    const int l32  = lane & 31;
    const int lh   = lane >> 5;       // channel-of-pair; D-row +4*lh

    const int row = blockIdx.x * 4 + wv;   // image row 0..31
    const int b   = blockIdx.y;
    const int kq  = blockIdx.z;            // K-quarter: channels [kq*16, kq*16+16)

    const unsigned short* AhU = (const unsigned short*)Ah;
    const float4* wsrc = (const float4*)Wt;

    f32x16 acc[2][2];                 // [nt][kpos parity]
#pragma unroll
    for (int nt = 0; nt < 2; ++nt)
#pragma unroll
        for (int e = 0; e < 2; ++e)
#pragma unroll
            for (int r = 0; r < 16; ++r) acc[nt][e][r] = 0.f;

    for (int ig2 = 0; ig2 < 2; ++ig2) {
        const int ig = kq * 2 + ig2;
        __syncthreads();
#pragma unroll
        for (int p = 0; p < 18; ++p)
            ((float4*)Wlds)[p * 256 + tid] = wsrc[(size_t)ig * 4608 + p * 256 + tid];
        __syncthreads();

#pragma unroll
        for (int ipair = 0; ipair < 4; ++ipair) {
            const unsigned short* ap = AhU +
                ((size_t)(b * CIN + ig * 8 + ipair * 2 + lh) * AHC + (row + 1) * AH + 1 + l32) * NS;
            const unsigned short* wb = Wlds + ((ipair * 2 + lh) * 9) * COUT * NS + l32 * NS;
#pragma unroll
            for (int kpos = 0; kpos < 9; ++kpos) {
                const int dy = kpos / 3 - 1, dx = kpos % 3 - 1;
                short8 af = *(const short8*)(ap + (dy * AH + dx) * NS);
#pragma unroll
                for (int nt = 0; nt < 2; ++nt) {
                    short8 wf = *(const short8*)(wb + (kpos * COUT + nt * 32) * NS);
                    if (kpos & 1)
                        acc[nt][1] = __builtin_amdgcn_mfma_f32_32x32x16_bf16(wf, af, acc[nt][1], 0, 0, 0);
                    else
                        acc[nt][0] = __builtin_amdgcn_mfma_f32_32x32x16_bf16(wf, af, acc[nt][0], 0, 0, 0);
                }
            }
        }
    }

    // D: col(pix)=l32, row(o_local)=(r&3)+8*(r>>2)+4*lh ; split-K partial -> atomicAdd
    const int pixb = row * HW + l32;
#pragma unroll
    for (int nt = 0; nt < 2; ++nt) {
#pragma unroll
        for (int r = 0; r < 16; ++r) {
            const int o = nt * 32 + (r & 3) + 8 * (r >> 2) + 4 * lh;
            float v = acc[nt][0][r] + acc[nt][1][r];
            if (kq == 0) v += bias[o];
            atomicAdd(&out[(size_t)(b * COUT + o) * LL + pixb], v);
        }
    }
}

extern "C" void kernel_launch(void* const* d_in, const int* in_sizes, int n_in,
                              void* d_out, int out_size, void* d_ws, size_t ws_size,
                              hipStream_t stream) {
    const float* x = (const float*)d_in[0];
    const float* w = (const float*)d_in[1];
    const float* c = (const float*)d_in[2];
    float* out = (float*)d_out;

    char* ws = (char*)d_ws;
    __hip_bfloat16* Wt   = (__hip_bfloat16*)(ws);
    float*          bias = (float*)(ws + 589824);
    __hip_bfloat16* Ah   = (__hip_bfloat16*)(ws + 590080);

    // 4624 act blocks + 4096 out-init blocks + 145 prep blocks = 8865
    prep_act_kernel<<<8865, 256, 0, stream>>>(x, w, c, Wt, bias, Ah, out);
    kan_mfma_kernel<<<dim3(8, 16, 4), 256, 0, stream>>>(Wt, bias, Ah, out);
}

// Round 7
// 112.862 us; speedup vs baseline: 1.0818x; 1.0818x over previous
//
#include <hip/hip_runtime.h>
#include <hip/hip_bf16.h>

// Conv2dKan via implicit-GEMM MFMA (16x16x32 bf16). b=16, cin=cout=64, H=W=32, K=3, PAD=1, BASIS=8.
// out[b,o,pix] = bias[o] + sum_{i,k,s8} Wt[i,k,o,s]*Ah[b,i,pix+off(k),s]
//   Wt[...,0]=w, Wt[...,s]=w*c[s] (s=1..7), bf16   layout [i][kpos][o][s]
//   Ah = [silu(x), T1..T7(tanh x)] on 34x34 halo grid; border = act(0) = [0,0,-1,0,1,0,-1,0]
//   bias[o] = sum_{i,k} w*c[...,0]  (T0==1)
// Frag layouts (HW-verified R3/R5): 16x16x32 A/B: lane=(quad,l16), k=quad*8+s, m/n=l16;
//   C/D: col=l16, row=quad*4+r.
// R7: in-block split-K (no atomics, no out-init). Block 256thr = 4 waves =
//   (khalf x row): M=64pix x N=32o, wave = 32pix x 32o x 32ch, P=2 pixel-group
//   register blocking (af:MFMA = wf:MFMA = 1:2). LDS = 2 x 18432B weight chunks
//   (4ch each) = 36864B -> 512 blocks = 2 blocks/CU = 2 waves/SIMD on all CUs.
//   Epilogue: khalf partials reduced via padded LDS ([64][33]), direct stores.

#define CIN   64
#define COUT  64
#define HW    32
#define LL    1024
#define NS    8
#define AH    34
#define AHC   1156

typedef __attribute__((ext_vector_type(8))) short short8;
typedef __attribute__((ext_vector_type(4))) float f32x4;

// ws layout (bytes):
//   [0)       Wt   : 64*9*64*8 bf16 = 589824 B   ([i][kpos][o][s])
//   [589824)  bias : 64 f32         = 256 B
//   [590080)  Ah   : 16*64*1156*8 bf16 = 18939904 B

__global__ void prep_act_kernel(const float* __restrict__ x,
                                const float* __restrict__ w,
                                const float* __restrict__ c,
                                __hip_bfloat16* __restrict__ Wt,
                                float* __restrict__ bias,
                                __hip_bfloat16* __restrict__ Ah) {
    int bx = blockIdx.x;
    if (bx >= 4624) {
        bx -= 4624;                      // prep part: 145 blocks
        if (bx == 144) {
            // bias[o] = sum_{i,k} w[i,o,k]*c[i,o,k,0]
            __shared__ float red[256];
            const int o = threadIdx.x & 63;
            const int part = threadIdx.x >> 6;
            float v = 0.f;
            for (int ii = 0; ii < 16; ++ii) {
                const int i = part * 16 + ii;
#pragma unroll
                for (int k = 0; k < 9; ++k) {
                    const int idx = (i * COUT + o) * 9 + k;
                    v += w[idx] * c[idx * 8];
                }
            }
            red[threadIdx.x] = v;
            __syncthreads();
            if (part == 0) bias[o] = red[o] + red[64 + o] + red[128 + o] + red[192 + o];
            return;
        }
        const int tid = bx * 256 + threadIdx.x;   // < 36864 = 64i*9k*64o
        const int i = tid / (9 * COUT);
        const int r = tid - i * 9 * COUT;
        const int k = r / COUT;
        const int o = r - k * COUT;
        const int widx = (i * COUT + o) * 9 + k;
        const float wv = w[widx];
        __hip_bfloat16* dst = Wt + (size_t)tid * NS;   // tid == (i*9+k)*64+o
        dst[0] = __float2bfloat16(wv);
#pragma unroll
        for (int s = 1; s < 8; ++s) dst[s] = __float2bfloat16(wv * c[widx * 8 + s]);
        return;
    }

    // act part: 4624 blocks, 1,183,744 threads = 16*64*1156 halo cells
    const int idx = bx * 256 + threadIdx.x;
    const int bi = idx / AHC;
    const int r  = idx - bi * AHC;
    const int yy = r / AH;
    const int xx = r - yy * AH;
    __align__(16) __hip_bfloat16 hv[8];
    if (yy >= 1 && yy <= 32 && xx >= 1 && xx <= 32) {
        float xv = x[bi * LL + (yy - 1) * HW + (xx - 1)];
        float e  = __expf(-xv);
        float res = xv / (1.f + e);              // silu
        float e2 = __expf(2.f * xv);
        float t  = 1.f - 2.f / (e2 + 1.f);       // tanh
        float T2 = 2.f * t * t  - 1.f;
        float T3 = 2.f * t * T2 - t;
        float T4 = 2.f * t * T3 - T2;
        float T5 = 2.f * t * T4 - T3;
        float T6 = 2.f * t * T5 - T4;
        float T7 = 2.f * t * T6 - T5;
        hv[0] = __float2bfloat16(res); hv[1] = __float2bfloat16(t);
        hv[2] = __float2bfloat16(T2);  hv[3] = __float2bfloat16(T3);
        hv[4] = __float2bfloat16(T4);  hv[5] = __float2bfloat16(T5);
        hv[6] = __float2bfloat16(T6);  hv[7] = __float2bfloat16(T7);
    } else {
        // activation of x=0: [0, 0, -1, 0, 1, 0, -1, 0]
        ((unsigned int*)hv)[0] = 0x00000000u;
        ((unsigned int*)hv)[1] = 0x0000BF80u;
        ((unsigned int*)hv)[2] = 0x00003F80u;
        ((unsigned int*)hv)[3] = 0x0000BF80u;
    }
    *(float4*)(Ah + (size_t)idx * NS) = *(const float4*)hv;
}

// grid (16 row-pairs, 16 batches, 2 o-halves), block 256 = 4 waves (khalf x pg-row).
// Wave: 32 pix (row y0+pg) x 32 o x K-half (32 ch as 8 chunks of 4ch).
__global__ __launch_bounds__(256) void kan_mfma_kernel(
        const __hip_bfloat16* __restrict__ Wt,
        const float* __restrict__ bias,
        const __hip_bfloat16* __restrict__ Ah,
        float* __restrict__ out) {
    // weights: [kh 2][il 4][k 9][o 32] float4(=8bf16) = 2304 float4 = 36864 B
    // epilogue overlay: float [2][64][33] = 16896 B
    __shared__ __align__(16) unsigned short Wlds[18432];

    const int tid   = threadIdx.x;
    const int wv    = tid >> 6;
    const int lane  = tid & 63;
    const int quad  = lane >> 4;      // channel within 4-ch chunk
    const int l16   = lane & 15;
    const int khalf = wv >> 1;        // K-half: channels [khalf*32, khalf*32+32)
    const int pg    = wv & 1;         // row within pair

    const int y0 = blockIdx.x * 2;
    const int b  = blockIdx.y;
    const int oh = blockIdx.z;        // o-half: [oh*32, oh*32+32)
    const int row = y0 + pg;

    const unsigned short* AhU = (const unsigned short*)Ah;
    const float4* wsrc = (const float4*)Wt;   // float4 idx = (i*9+k)*64 + o

    f32x4 acc[2][2];                  // [h pixel-group][nt]
#pragma unroll
    for (int h = 0; h < 2; ++h)
#pragma unroll
        for (int nt = 0; nt < 2; ++nt) acc[h][nt] = (f32x4){0.f, 0.f, 0.f, 0.f};

    for (int step = 0; step < 8; ++step) {
        __syncthreads();
        // stage 2304 float4 (both khalf chunks), 9 per thread
#pragma unroll
        for (int p = 0; p < 9; ++p) {
            const int j  = p * 256 + tid;
            const int kh = (j >= 1152);
            const int jj = j - (kh ? 1152 : 0);
            const int il = jj / 288;
            const int r2 = jj - il * 288;
            const int k  = r2 >> 5;
            const int oo = r2 & 31;
            ((float4*)Wlds)[j] =
                wsrc[(size_t)(((kh * 32 + step * 4 + il) * 9 + k) << 6) + (oh << 5) + oo];
        }
        __syncthreads();

        const int ch = khalf * 32 + step * 4 + quad;
        const unsigned short* ap = AhU +
            ((size_t)(b * CIN + ch) * AHC + (row + 1) * AH + 1) * NS;
        const unsigned short* wb = Wlds + khalf * 9216;   // 1152 float4 = 9216 ushorts
#pragma unroll
        for (int kpos = 0; kpos < 9; ++kpos) {
            const int dy = kpos / 3 - 1, dx = kpos % 3 - 1;
            short8 af0 = *(const short8*)(ap + (dy * AH + dx + l16) * NS);
            short8 af1 = *(const short8*)(ap + (dy * AH + dx + 16 + l16) * NS);
#pragma unroll
            for (int nt = 0; nt < 2; ++nt) {
                short8 wf = *(const short8*)(wb + ((quad * 9 + kpos) * 32 + nt * 16 + l16) * NS);
                acc[0][nt] = __builtin_amdgcn_mfma_f32_16x16x32_bf16(wf, af0, acc[0][nt], 0, 0, 0);
                acc[1][nt] = __builtin_amdgcn_mfma_f32_16x16x32_bf16(wf, af1, acc[1][nt], 0, 0, 0);
            }
        }
    }

    // reduce the two K-halves via LDS: red[khalf][pixl 64][ol 33 padded]
    __syncthreads();
    float* red = (float*)Wlds;
#pragma unroll
    for (int h = 0; h < 2; ++h)
#pragma unroll
        for (int nt = 0; nt < 2; ++nt)
#pragma unroll
            for (int r = 0; r < 4; ++r) {
                const int pixl = pg * 32 + h * 16 + l16;
                const int ol   = nt * 16 + quad * 4 + r;
                red[(khalf * 64 + pixl) * 33 + ol] = acc[h][nt][r];
            }
    __syncthreads();

#pragma unroll
    for (int rep = 0; rep < 8; ++rep) {
        const int v = rep * 256 + tid;     // 2048 = 64 pix x 32 o
        const int pixl = v & 63;
        const int ol   = v >> 6;
        const int o    = (oh << 5) + ol;
        const float s  = red[pixl * 33 + ol] + red[(64 + pixl) * 33 + ol] + bias[o];
        out[(size_t)(b * COUT + o) * LL + (y0 + (pixl >> 5)) * HW + (pixl & 31)] = s;
    }
}

extern "C" void kernel_launch(void* const* d_in, const int* in_sizes, int n_in,
                              void* d_out, int out_size, void* d_ws, size_t ws_size,
                              hipStream_t stream) {
    const float* x = (const float*)d_in[0];
    const float* w = (const float*)d_in[1];
    const float* c = (const float*)d_in[2];
    float* out = (float*)d_out;

    char* ws = (char*)d_ws;
    __hip_bfloat16* Wt   = (__hip_bfloat16*)(ws);
    float*          bias = (float*)(ws + 589824);
    __hip_bfloat16* Ah   = (__hip_bfloat16*)(ws + 590080);

    prep_act_kernel<<<4769, 256, 0, stream>>>(x, w, c, Wt, bias, Ah);
    kan_mfma_kernel<<<dim3(16, 16, 2), 256, 0, stream>>>(Wt, bias, Ah, out);
}

// Round 8
// 90.944 us; speedup vs baseline: 1.3425x; 1.2410x over previous
//
#include <hip/hip_runtime.h>
#include <hip/hip_bf16.h>

// Conv2dKan via implicit-GEMM MFMA (16x16x32 bf16). b=16, cin=cout=64, H=W=32, K=3, PAD=1, BASIS=8.
// out[b,o,pix] = bias[o] + sum_{i,k,s8} Wt[i,k,o,s]*Ah[b,i,pix+off(k),s]
//   Wt[...,0]=w, Wt[...,s]=w*c[s] (s=1..7), bf16   layout [i][kpos][o][s]
//   Ah = [silu(x), T1..T7(tanh x)] on 34x34 halo grid; border = act(0) = [0,0,-1,0,1,0,-1,0]
//   bias[o] = sum_{i,k} w*c[...,0]  (T0==1)
// Frag layouts (HW-verified R3/R5): 16x16x32 A/B: lane=(quad,l16), k=quad*8+s, m/n=l16;
//   C/D: col=l16, row=quad*4+r.
// R8: R7 main unchanged (in-block split-K, 2 blocks/CU). Fix: the fused-prep bias
//   block was ONE block doing 36864 gathered loads (~40us serial tail, the real
//   reason R4-R7 totals regressed). Bias now 64 parallel blocks (R3's verified
//   shuffle-reduce). Kernel time = max over blocks -> all parts must be parallel.

#define CIN   64
#define COUT  64
#define HW    32
#define LL    1024
#define NS    8
#define AH    34
#define AHC   1156

typedef __attribute__((ext_vector_type(8))) short short8;
typedef __attribute__((ext_vector_type(4))) float f32x4;

// ws layout (bytes):
//   [0)       Wt   : 64*9*64*8 bf16 = 589824 B   ([i][kpos][o][s])
//   [589824)  bias : 64 f32         = 256 B
//   [590080)  Ah   : 16*64*1156*8 bf16 = 18939904 B

__global__ void prep_act_kernel(const float* __restrict__ x,
                                const float* __restrict__ w,
                                const float* __restrict__ c,
                                __hip_bfloat16* __restrict__ Wt,
                                float* __restrict__ bias,
                                __hip_bfloat16* __restrict__ Ah) {
    int bx = blockIdx.x;
    if (bx >= 4624) {
        bx -= 4624;
        if (bx >= 144) {
            // bias part: 64 parallel blocks, one o each; 64-lane wave reduce over i.
            const int o = bx - 144;
            const int i = threadIdx.x;       // lanes 0..63 participate
            if (i >= 64) return;
            float v = 0.f;
#pragma unroll
            for (int k = 0; k < 9; ++k) {
                const int idx = (i * COUT + o) * 9 + k;
                v += w[idx] * c[idx * 8];
            }
#pragma unroll
            for (int off = 32; off > 0; off >>= 1) v += __shfl_down(v, off);
            if (i == 0) bias[o] = v;
            return;
        }
        // Wt part: 144 blocks
        const int tid = bx * 256 + threadIdx.x;   // < 36864 = 64i*9k*64o
        const int i = tid / (9 * COUT);
        const int r = tid - i * 9 * COUT;
        const int k = r / COUT;
        const int o = r - k * COUT;
        const int widx = (i * COUT + o) * 9 + k;
        const float wv = w[widx];
        __hip_bfloat16* dst = Wt + (size_t)tid * NS;   // tid == (i*9+k)*64+o
        dst[0] = __float2bfloat16(wv);
#pragma unroll
        for (int s = 1; s < 8; ++s) dst[s] = __float2bfloat16(wv * c[widx * 8 + s]);
        return;
    }

    // act part: 4624 blocks, 1,183,744 threads = 16*64*1156 halo cells
    const int idx = bx * 256 + threadIdx.x;
    const int bi = idx / AHC;
    const int r  = idx - bi * AHC;
    const int yy = r / AH;
    const int xx = r - yy * AH;
    __align__(16) __hip_bfloat16 hv[8];
    if (yy >= 1 && yy <= 32 && xx >= 1 && xx <= 32) {
        float xv = x[bi * LL + (yy - 1) * HW + (xx - 1)];
        float e  = __expf(-xv);
        float res = xv / (1.f + e);              // silu
        float e2 = __expf(2.f * xv);
        float t  = 1.f - 2.f / (e2 + 1.f);       // tanh
        float T2 = 2.f * t * t  - 1.f;
        float T3 = 2.f * t * T2 - t;
        float T4 = 2.f * t * T3 - T2;
        float T5 = 2.f * t * T4 - T3;
        float T6 = 2.f * t * T5 - T4;
        float T7 = 2.f * t * T6 - T5;
        hv[0] = __float2bfloat16(res); hv[1] = __float2bfloat16(t);
        hv[2] = __float2bfloat16(T2);  hv[3] = __float2bfloat16(T3);
        hv[4] = __float2bfloat16(T4);  hv[5] = __float2bfloat16(T5);
        hv[6] = __float2bfloat16(T6);  hv[7] = __float2bfloat16(T7);
    } else {
        // activation of x=0: [0, 0, -1, 0, 1, 0, -1, 0]
        ((unsigned int*)hv)[0] = 0x00000000u;
        ((unsigned int*)hv)[1] = 0x0000BF80u;
        ((unsigned int*)hv)[2] = 0x00003F80u;
        ((unsigned int*)hv)[3] = 0x0000BF80u;
    }
    *(float4*)(Ah + (size_t)idx * NS) = *(const float4*)hv;
}

// grid (16 row-pairs, 16 batches, 2 o-halves), block 256 = 4 waves (khalf x pg-row).
// Wave: 32 pix (row y0+pg) x 32 o x K-half (32 ch as 8 chunks of 4ch).
__global__ __launch_bounds__(256) void kan_mfma_kernel(
        const __hip_bfloat16* __restrict__ Wt,
        const float* __restrict__ bias,
        const __hip_bfloat16* __restrict__ Ah,
        float* __restrict__ out) {
    // weights: [kh 2][il 4][k 9][o 32] float4(=8bf16) = 2304 float4 = 36864 B
    // epilogue overlay: float [2][64][33] = 16896 B
    __shared__ __align__(16) unsigned short Wlds[18432];

    const int tid   = threadIdx.x;
    const int wv    = tid >> 6;
    const int lane  = tid & 63;
    const int quad  = lane >> 4;      // channel within 4-ch chunk
    const int l16   = lane & 15;
    const int khalf = wv >> 1;        // K-half: channels [khalf*32, khalf*32+32)
    const int pg    = wv & 1;         // row within pair

    const int y0 = blockIdx.x * 2;
    const int b  = blockIdx.y;
    const int oh = blockIdx.z;        // o-half: [oh*32, oh*32+32)
    const int row = y0 + pg;

    const unsigned short* AhU = (const unsigned short*)Ah;
    const float4* wsrc = (const float4*)Wt;   // float4 idx = (i*9+k)*64 + o

    f32x4 acc[2][2];                  // [h pixel-group][nt]
#pragma unroll
    for (int h = 0; h < 2; ++h)
#pragma unroll
        for (int nt = 0; nt < 2; ++nt) acc[h][nt] = (f32x4){0.f, 0.f, 0.f, 0.f};

    for (int step = 0; step < 8; ++step) {
        __syncthreads();
        // stage 2304 float4 (both khalf chunks), 9 per thread
#pragma unroll
        for (int p = 0; p < 9; ++p) {
            const int j  = p * 256 + tid;
            const int kh = (j >= 1152);
            const int jj = j - (kh ? 1152 : 0);
            const int il = jj / 288;
            const int r2 = jj - il * 288;
            const int k  = r2 >> 5;
            const int oo = r2 & 31;
            ((float4*)Wlds)[j] =
                wsrc[(size_t)(((kh * 32 + step * 4 + il) * 9 + k) << 6) + (oh << 5) + oo];
        }
        __syncthreads();

        const int ch = khalf * 32 + step * 4 + quad;
        const unsigned short* ap = AhU +
            ((size_t)(b * CIN + ch) * AHC + (row + 1) * AH + 1) * NS;
        const unsigned short* wb = Wlds + khalf * 9216;   // 1152 float4 = 9216 ushorts
#pragma unroll
        for (int kpos = 0; kpos < 9; ++kpos) {
            const int dy = kpos / 3 - 1, dx = kpos % 3 - 1;
            short8 af0 = *(const short8*)(ap + (dy * AH + dx + l16) * NS);
            short8 af1 = *(const short8*)(ap + (dy * AH + dx + 16 + l16) * NS);
#pragma unroll
            for (int nt = 0; nt < 2; ++nt) {
                short8 wf = *(const short8*)(wb + ((quad * 9 + kpos) * 32 + nt * 16 + l16) * NS);
                acc[0][nt] = __builtin_amdgcn_mfma_f32_16x16x32_bf16(wf, af0, acc[0][nt], 0, 0, 0);
                acc[1][nt] = __builtin_amdgcn_mfma_f32_16x16x32_bf16(wf, af1, acc[1][nt], 0, 0, 0);
            }
        }
    }

    // reduce the two K-halves via LDS: red[khalf][pixl 64][ol 33 padded]
    __syncthreads();
    float* red = (float*)Wlds;
#pragma unroll
    for (int h = 0; h < 2; ++h)
#pragma unroll
        for (int nt = 0; nt < 2; ++nt)
#pragma unroll
            for (int r = 0; r < 4; ++r) {
                const int pixl = pg * 32 + h * 16 + l16;
                const int ol   = nt * 16 + quad * 4 + r;
                red[(khalf * 64 + pixl) * 33 + ol] = acc[h][nt][r];
            }
    __syncthreads();

#pragma unroll
    for (int rep = 0; rep < 8; ++rep) {
        const int v = rep * 256 + tid;     // 2048 = 64 pix x 32 o
        const int pixl = v & 63;
        const int ol   = v >> 6;
        const int o    = (oh << 5) + ol;
        const float s  = red[pixl * 33 + ol] + red[(64 + pixl) * 33 + ol] + bias[o];
        out[(size_t)(b * COUT + o) * LL + (y0 + (pixl >> 5)) * HW + (pixl & 31)] = s;
    }
}

extern "C" void kernel_launch(void* const* d_in, const int* in_sizes, int n_in,
                              void* d_out, int out_size, void* d_ws, size_t ws_size,
                              hipStream_t stream) {
    const float* x = (const float*)d_in[0];
    const float* w = (const float*)d_in[1];
    const float* c = (const float*)d_in[2];
    float* out = (float*)d_out;

    char* ws = (char*)d_ws;
    __hip_bfloat16* Wt   = (__hip_bfloat16*)(ws);
    float*          bias = (float*)(ws + 589824);
    __hip_bfloat16* Ah   = (__hip_bfloat16*)(ws + 590080);

    // 4624 act blocks + 144 Wt blocks + 64 bias blocks = 4832, all parallel
    prep_act_kernel<<<4832, 256, 0, stream>>>(x, w, c, Wt, bias, Ah);
    kan_mfma_kernel<<<dim3(16, 16, 2), 256, 0, stream>>>(Wt, bias, Ah, out);
}